// Round 2
// baseline (177.687 us; speedup 1.0000x reference)
//
#include <hip/hip_runtime.h>
#include <math.h>

#define S_LEN 1024
#define DM    256
#define DU    32
#define TEMPF 5.0f

// ---------------------------------------------------------------------------
// Kernel A: fused QKV projection.  out = act(x @ W + b), act = sigmoid for
// Q,K (mat 0,1), identity for V (mat 2). Writes [h][s][du] layout to ws.
// Grid (4 Ntiles, 16 Mtiles, 3 mats), 256 threads, 64x64 tile, 4x4 micro.
// ---------------------------------------------------------------------------
__global__ __launch_bounds__(256) void qkv_proj_kernel(
    const float* __restrict__ x,
    const float* __restrict__ Wq, const float* __restrict__ bq,
    const float* __restrict__ Wk, const float* __restrict__ bk,
    const float* __restrict__ Wv, const float* __restrict__ bv,
    float* __restrict__ qo, float* __restrict__ ko, float* __restrict__ vo)
{
    const int mat = blockIdx.z;
    const float* __restrict__ W    = (mat == 0) ? Wq : ((mat == 1) ? Wk : Wv);
    const float* __restrict__ bias = (mat == 0) ? bq : ((mat == 1) ? bk : bv);
    float* __restrict__ dst        = (mat == 0) ? qo : ((mat == 1) ? ko : vo);

    const int n0 = blockIdx.x * 64;
    const int m0 = blockIdx.y * 64;
    const int t  = threadIdx.x;
    const int tx = t & 15;        // col group (0..15) -> cols tx*4..tx*4+3
    const int ty = t >> 4;        // row group (0..15) -> rows ty*4..ty*4+3

    __shared__ float xs[64][17];  // [row][k], +1 pad
    __shared__ float ws[16][68];  // [k][n],  +4 pad (16B-aligned rows)

    float acc[4][4] = {};

    const int xr = t >> 2;          // 0..63  (x tile row)
    const int xk = (t & 3) * 4;     // 0,4,8,12
    const int wk = t >> 4;          // 0..15  (W tile k)
    const int wn = (t & 15) * 4;    // 0..60

    for (int k0 = 0; k0 < DM; k0 += 16) {
        float4 xv = *(const float4*)&x[(m0 + xr) * DM + k0 + xk];
        float4 wv = *(const float4*)&W[(k0 + wk) * DM + n0 + wn];
        __syncthreads();            // protect previous iteration's reads
        xs[xr][xk + 0] = xv.x; xs[xr][xk + 1] = xv.y;
        xs[xr][xk + 2] = xv.z; xs[xr][xk + 3] = xv.w;
        *(float4*)&ws[wk][wn] = wv;
        __syncthreads();
        #pragma unroll
        for (int kk = 0; kk < 16; kk++) {
            float a[4], b[4];
            #pragma unroll
            for (int i = 0; i < 4; i++) a[i] = xs[ty * 4 + i][kk];
            #pragma unroll
            for (int j = 0; j < 4; j++) b[j] = ws[kk][tx * 4 + j];
            #pragma unroll
            for (int i = 0; i < 4; i++)
                #pragma unroll
                for (int j = 0; j < 4; j++)
                    acc[i][j] += a[i] * b[j];
        }
    }

    #pragma unroll
    for (int j = 0; j < 4; j++) {
        const int cidx = n0 + tx * 4 + j;
        const float bb = bias[cidx];
        const int hh = cidx >> 5;   // head
        const int dd = cidx & 31;   // dim within head
        #pragma unroll
        for (int i = 0; i < 4; i++) {
            const int row = m0 + ty * 4 + i;
            float val = acc[i][j] + bb;
            if (mat < 2) val = 1.0f / (1.0f + __expf(-val));   // sigmoid
            dst[hh * (S_LEN * DU) + row * DU + dd] = val;
        }
    }
}

// ---------------------------------------------------------------------------
// Kernel B: fused fuzzy-implication attention (flash-style, causal).
// truth_ij = 1 - (1/32) * sum_d relu(Q[i][d] - K[j][d]);  z = TEMP*truth
// Grid: 8 heads * 64 i-tiles (16 rows each) = 512 blocks, 256 threads.
// Thread (r,c): r = row in tile (0..15), c = lane-in-row (0..15).
// Scores: thread (r,c) computes columns jj = c+16*q4 (q4=0..3).
// m/l row reductions via 16-lane shfl_xor butterflies (dim-free -> valid).
// PV: p staged in LDS Ps[r][j]; each lane then owns output dims d=c, d=c+16
// and loops all 64 j  (broadcast read of Ps[r][j], conflict-free Vs[j][c]).
// ---------------------------------------------------------------------------
__global__ __launch_bounds__(256) void attn_kernel(
    const float* __restrict__ q, const float* __restrict__ k,
    const float* __restrict__ v, float* __restrict__ attn)
{
    const int h  = blockIdx.x >> 6;
    const int it = blockIdx.x & 63;
    const int i0 = it * 16;
    const int t  = threadIdx.x;
    const int r  = t >> 4;      // 0..15
    const int c  = t & 15;      // 0..15
    const int ig = i0 + r;      // global query row

    __shared__ float Ks[64][36];   // +4 pad: conflict-free float4 reads
    __shared__ float Vs[64][36];
    __shared__ float Ps[16][68];   // p row stage; pad 68 decorrelates rows

    // Q row into registers (32 VGPRs), reused across all j-tiles
    float qreg[32];
    {
        const float* qrow = q + h * (S_LEN * DU) + ig * DU;
        #pragma unroll
        for (int d4 = 0; d4 < 8; d4++) {
            float4 qv = *(const float4*)&qrow[d4 * 4];
            qreg[d4 * 4 + 0] = qv.x; qreg[d4 * 4 + 1] = qv.y;
            qreg[d4 * 4 + 2] = qv.z; qreg[d4 * 4 + 3] = qv.w;
        }
    }

    float m = -1e30f, l = 0.0f, o0 = 0.0f, o1 = 0.0f;

    const int njt = (i0 + 15) / 64 + 1;   // causal: j-tiles covering j <= i0+15
    for (int jt = 0; jt < njt; jt++) {
        __syncthreads();   // protect Ks/Vs/Ps from previous iteration's readers
        {
            const int jr = t >> 2;            // 0..63
            const int d0 = (t & 3) * 8;       // 0,8,16,24
            const float* kp = k + h * (S_LEN * DU) + (jt * 64 + jr) * DU + d0;
            const float* vp = v + h * (S_LEN * DU) + (jt * 64 + jr) * DU + d0;
            float4 ka = *(const float4*)kp, kb = *(const float4*)(kp + 4);
            float4 va = *(const float4*)vp, vb = *(const float4*)(vp + 4);
            *(float4*)&Ks[jr][d0]     = ka;
            *(float4*)&Ks[jr][d0 + 4] = kb;
            *(float4*)&Vs[jr][d0]     = va;
            *(float4*)&Vs[jr][d0 + 4] = vb;
        }
        __syncthreads();

        // ---- scores for this thread's 4 columns: jj = c + 16*q4 ----
        float zv[4];
        #pragma unroll
        for (int q4 = 0; q4 < 4; q4++) {
            const int jj  = c + q4 * 16;
            const int jgl = jt * 64 + jj;
            float s = 0.0f;
            #pragma unroll
            for (int d = 0; d < 32; d += 4) {
                float4 kk4 = *(const float4*)&Ks[jj][d];
                s += fmaxf(qreg[d + 0] - kk4.x, 0.0f)
                   + fmaxf(qreg[d + 1] - kk4.y, 0.0f)
                   + fmaxf(qreg[d + 2] - kk4.z, 0.0f)
                   + fmaxf(qreg[d + 3] - kk4.w, 0.0f);
            }
            // z = TEMP * (1 - s/32); masked -> -1e30
            zv[q4] = (jgl <= ig) ? (TEMPF - (TEMPF / 32.0f) * s) : -1e30f;
        }

        // ---- online softmax state (row = 16 consecutive lanes) ----
        float mloc = fmaxf(fmaxf(zv[0], zv[1]), fmaxf(zv[2], zv[3]));
        #pragma unroll
        for (int off = 8; off; off >>= 1)
            mloc = fmaxf(mloc, __shfl_xor(mloc, off, 16));
        const float mnew  = fmaxf(m, mloc);
        const float alpha = __expf(m - mnew);

        float p[4];
        float lloc = 0.0f;
        #pragma unroll
        for (int q4 = 0; q4 < 4; q4++) {
            p[q4] = __expf(zv[q4] - mnew);     // masked z -> exp(-huge) = 0
            lloc += p[q4];
            Ps[r][c + q4 * 16] = p[q4];        // stage p row in LDS
        }
        #pragma unroll
        for (int off = 8; off; off >>= 1)
            lloc += __shfl_xor(lloc, off, 16);

        __syncthreads();   // Ps visible to whole row (and block)

        // ---- PV: lane owns dims d=c, d=c+16; loop all 64 j ----
        float pv0 = 0.0f, pv1 = 0.0f;
        #pragma unroll 8
        for (int j = 0; j < 64; j++) {
            const float pj = Ps[r][j];         // broadcast within row
            pv0 += pj * Vs[j][c];
            pv1 += pj * Vs[j][c + 16];
        }

        m  = mnew;
        l  = l  * alpha + lloc;
        o0 = o0 * alpha + pv0;
        o1 = o1 * alpha + pv1;
    }

    const float inv = 1.0f / l;
    // attn laid out [s][256] for the output projection
    attn[ig * DM + h * DU + c]      = o0 * inv;
    attn[ig * DM + h * DU + c + 16] = o1 * inv;
}

// ---------------------------------------------------------------------------
// Kernel C: output projection  out = attn @ Wo + bo   (plain [s][256] store)
// ---------------------------------------------------------------------------
__global__ __launch_bounds__(256) void out_proj_kernel(
    const float* __restrict__ a, const float* __restrict__ W,
    const float* __restrict__ bias, float* __restrict__ dst)
{
    const int n0 = blockIdx.x * 64;
    const int m0 = blockIdx.y * 64;
    const int t  = threadIdx.x;
    const int tx = t & 15;
    const int ty = t >> 4;

    __shared__ float xs[64][17];
    __shared__ float ws[16][68];

    float acc[4][4] = {};

    const int xr = t >> 2;
    const int xk = (t & 3) * 4;
    const int wk = t >> 4;
    const int wn = (t & 15) * 4;

    for (int k0 = 0; k0 < DM; k0 += 16) {
        float4 xv = *(const float4*)&a[(m0 + xr) * DM + k0 + xk];
        float4 wv = *(const float4*)&W[(k0 + wk) * DM + n0 + wn];
        __syncthreads();
        xs[xr][xk + 0] = xv.x; xs[xr][xk + 1] = xv.y;
        xs[xr][xk + 2] = xv.z; xs[xr][xk + 3] = xv.w;
        *(float4*)&ws[wk][wn] = wv;
        __syncthreads();
        #pragma unroll
        for (int kk = 0; kk < 16; kk++) {
            float av[4], bv[4];
            #pragma unroll
            for (int i = 0; i < 4; i++) av[i] = xs[ty * 4 + i][kk];
            #pragma unroll
            for (int j = 0; j < 4; j++) bv[j] = ws[kk][tx * 4 + j];
            #pragma unroll
            for (int i = 0; i < 4; i++)
                #pragma unroll
                for (int j = 0; j < 4; j++)
                    acc[i][j] += av[i] * bv[j];
        }
    }

    #pragma unroll
    for (int j = 0; j < 4; j++) {
        const int cidx = n0 + tx * 4 + j;
        const float bb = bias[cidx];
        #pragma unroll
        for (int i = 0; i < 4; i++) {
            const int row = m0 + ty * 4 + i;
            dst[row * DM + cidx] = acc[i][j] + bb;
        }
    }
}

// ---------------------------------------------------------------------------
extern "C" void kernel_launch(void* const* d_in, const int* in_sizes, int n_in,
                              void* d_out, int out_size, void* d_ws, size_t ws_size,
                              hipStream_t stream)
{
    const float* x  = (const float*)d_in[0];
    const float* Wq = (const float*)d_in[1];
    const float* bq = (const float*)d_in[2];
    const float* Wk = (const float*)d_in[3];
    const float* bk = (const float*)d_in[4];
    const float* Wv = (const float*)d_in[5];
    const float* bv = (const float*)d_in[6];
    const float* Wo = (const float*)d_in[7];
    const float* bo = (const float*)d_in[8];
    float* out = (float*)d_out;

    float* ws   = (float*)d_ws;
    float* q    = ws;                    // [8][1024][32] = 262144 floats
    float* k    = q + 262144;
    float* v    = k + 262144;
    float* attn = v + 262144;            // [1024][256]
    // total: 4 MiB of workspace

    qkv_proj_kernel<<<dim3(4, 16, 3), 256, 0, stream>>>(x, Wq, bq, Wk, bk, Wv, bv, q, k, v);
    attn_kernel<<<dim3(512), 256, 0, stream>>>(q, k, v, attn);
    out_proj_kernel<<<dim3(4, 16, 1), 256, 0, stream>>>(attn, Wo, bo, out);
}

// Round 3
// 144.049 us; speedup vs baseline: 1.2335x; 1.2335x over previous
//
#include <hip/hip_runtime.h>
#include <math.h>

#define S_LEN 1024
#define DM    256
#define DU    32
#define TEMPF 5.0f

// ---------------------------------------------------------------------------
// Kernel A: fused QKV projection.  out = act(x @ W + b), act = sigmoid for
// Q,K (mat 0,1), identity for V (mat 2). Writes [h][s][du] layout to ws.
// 64x64 tile, BK=32, xs stored TRANSPOSED [k][row] so inner reads are b128.
// ---------------------------------------------------------------------------
__global__ __launch_bounds__(256) void qkv_proj_kernel(
    const float* __restrict__ x,
    const float* __restrict__ Wq, const float* __restrict__ bq,
    const float* __restrict__ Wk, const float* __restrict__ bk,
    const float* __restrict__ Wv, const float* __restrict__ bv,
    float* __restrict__ qo, float* __restrict__ ko, float* __restrict__ vo)
{
    const int mat = blockIdx.z;
    const float* __restrict__ W    = (mat == 0) ? Wq : ((mat == 1) ? Wk : Wv);
    const float* __restrict__ bias = (mat == 0) ? bq : ((mat == 1) ? bk : bv);
    float* __restrict__ dst        = (mat == 0) ? qo : ((mat == 1) ? ko : vo);

    const int n0 = blockIdx.x * 64;
    const int m0 = blockIdx.y * 64;
    const int t  = threadIdx.x;
    const int tx = t & 15;        // col group: cols tx*4..tx*4+3
    const int ty = t >> 4;        // row group: rows ty*4..ty*4+3

    __shared__ float xs[32][68];   // TRANSPOSED: [k][row]; pad 68
    __shared__ float wsh[32][68];  // [k][n]

    float acc[4][4] = {};

    // staging assignments
    const int lrow = t & 63;          // x row (wave-uniform k-chunk)
    const int lkc  = (t >> 6) * 8;    // x k-chunk 0/8/16/24
    const int wrow = t >> 4;          // W k row 0..15 (and +16)
    const int wcol = (t & 15) * 4;

    for (int k0 = 0; k0 < DM; k0 += 32) {
        const float* xp = &x[(m0 + lrow) * DM + k0 + lkc];
        float4 xa = *(const float4*)xp;
        float4 xb = *(const float4*)(xp + 4);
        const float* wp = &W[(k0 + wrow) * DM + n0 + wcol];
        float4 wa = *(const float4*)wp;
        float4 wb = *(const float4*)(wp + 16 * DM);
        __syncthreads();               // protect previous iteration's reads
        xs[lkc + 0][lrow] = xa.x; xs[lkc + 1][lrow] = xa.y;
        xs[lkc + 2][lrow] = xa.z; xs[lkc + 3][lrow] = xa.w;
        xs[lkc + 4][lrow] = xb.x; xs[lkc + 5][lrow] = xb.y;
        xs[lkc + 6][lrow] = xb.z; xs[lkc + 7][lrow] = xb.w;
        *(float4*)&wsh[wrow][wcol]      = wa;
        *(float4*)&wsh[wrow + 16][wcol] = wb;
        __syncthreads();
        #pragma unroll
        for (int kk = 0; kk < 32; kk++) {
            float4 a4 = *(const float4*)&xs[kk][ty * 4];
            float4 b4 = *(const float4*)&wsh[kk][tx * 4];
            acc[0][0] += a4.x * b4.x; acc[0][1] += a4.x * b4.y;
            acc[0][2] += a4.x * b4.z; acc[0][3] += a4.x * b4.w;
            acc[1][0] += a4.y * b4.x; acc[1][1] += a4.y * b4.y;
            acc[1][2] += a4.y * b4.z; acc[1][3] += a4.y * b4.w;
            acc[2][0] += a4.z * b4.x; acc[2][1] += a4.z * b4.y;
            acc[2][2] += a4.z * b4.z; acc[2][3] += a4.z * b4.w;
            acc[3][0] += a4.w * b4.x; acc[3][1] += a4.w * b4.y;
            acc[3][2] += a4.w * b4.z; acc[3][3] += a4.w * b4.w;
        }
    }

    #pragma unroll
    for (int j = 0; j < 4; j++) {
        const int cidx = n0 + tx * 4 + j;
        const float bb = bias[cidx];
        const int hh = cidx >> 5;   // head
        const int dd = cidx & 31;   // dim within head
        #pragma unroll
        for (int i = 0; i < 4; i++) {
            const int row = m0 + ty * 4 + i;
            float val = acc[i][j] + bb;
            if (mat < 2) val = 1.0f / (1.0f + __expf(-val));   // sigmoid
            dst[hh * (S_LEN * DU) + row * DU + dd] = val;
        }
    }
}

// ---------------------------------------------------------------------------
// Kernel B: fused fuzzy-implication attention (flash-style, causal).
// truth_ij = 1 - (1/32) * sum_d relu(Q[i][d] - K[j][d]);  z = TEMP*truth
// Grid: 512 blocks (8 heads x 64 i-tiles of 16 rows), 256 threads.
// LPT remap: longest blocks (it=63) dispatched first -> balanced tail.
// Thread (r,c): r = row in tile, c = lane-in-row; cols jj = c+16*q4.
// PV: Ps read as float4 (1 b128 / 4 j); V packed float2 {V[j][c],V[j][c+16]}
// (1 b64 per j instead of 2 b32). Ps is intra-wave only -> no barrier.
// ---------------------------------------------------------------------------
__global__ __launch_bounds__(256) void attn_kernel(
    const float* __restrict__ q, const float* __restrict__ k,
    const float* __restrict__ v, float* __restrict__ attn)
{
    const int h  = blockIdx.x & 7;
    const int it = 63 - (blockIdx.x >> 3);    // LPT: heavy i-tiles first
    const int i0 = it * 16;
    const int t  = threadIdx.x;
    const int r  = t >> 4;      // 0..15
    const int c  = t & 15;      // 0..15
    const int ig = i0 + r;      // global query row

    __shared__ float  Ks[64][36];     // +4 pad: conflict-free b128 reads
    __shared__ float2 Vs2[64][17];    // [j][c] = {V[j][c], V[j][c+16]}
    __shared__ float  Ps[16][68];     // p row stage (intra-wave use only)

    // Q row into registers, reused across all j-tiles
    float qreg[32];
    {
        const float* qrow = q + h * (S_LEN * DU) + ig * DU;
        #pragma unroll
        for (int d4 = 0; d4 < 8; d4++) {
            float4 qv = *(const float4*)&qrow[d4 * 4];
            qreg[d4 * 4 + 0] = qv.x; qreg[d4 * 4 + 1] = qv.y;
            qreg[d4 * 4 + 2] = qv.z; qreg[d4 * 4 + 3] = qv.w;
        }
    }

    float m = -1e30f, l = 0.0f, o0 = 0.0f, o1 = 0.0f;

    const int njt = it / 4 + 1;   // causal: j-tiles covering j <= i0+15
    for (int jt = 0; jt < njt; jt++) {
        __syncthreads();   // protect Ks/Vs2 from previous iteration's readers
        {
            const int jr = t >> 2;            // 0..63
            const int d0 = (t & 3) * 8;       // 0,8,16,24
            const float* kp = k + h * (S_LEN * DU) + (jt * 64 + jr) * DU + d0;
            const float* vp = v + h * (S_LEN * DU) + (jt * 64 + jr) * DU + d0;
            float4 ka = *(const float4*)kp, kb = *(const float4*)(kp + 4);
            float4 va = *(const float4*)vp, vb = *(const float4*)(vp + 4);
            *(float4*)&Ks[jr][d0]     = ka;
            *(float4*)&Ks[jr][d0 + 4] = kb;
            float vv[8] = {va.x, va.y, va.z, va.w, vb.x, vb.y, vb.z, vb.w};
            #pragma unroll
            for (int i = 0; i < 8; i++) {
                const int d = d0 + i;
                ((float*)&Vs2[jr][d & 15])[d >> 4] = vv[i];
            }
        }
        __syncthreads();

        // ---- scores for this thread's 4 columns: jj = c + 16*q4 ----
        float zv[4];
        #pragma unroll
        for (int q4 = 0; q4 < 4; q4++) {
            const int jj  = c + q4 * 16;
            const int jgl = jt * 64 + jj;
            float s = 0.0f;
            #pragma unroll
            for (int d = 0; d < 32; d += 4) {
                float4 kk4 = *(const float4*)&Ks[jj][d];
                s += fmaxf(qreg[d + 0] - kk4.x, 0.0f)
                   + fmaxf(qreg[d + 1] - kk4.y, 0.0f)
                   + fmaxf(qreg[d + 2] - kk4.z, 0.0f)
                   + fmaxf(qreg[d + 3] - kk4.w, 0.0f);
            }
            zv[q4] = (jgl <= ig) ? (TEMPF - (TEMPF / 32.0f) * s) : -1e30f;
        }

        // ---- online softmax state (row = 16 consecutive lanes) ----
        float mloc = fmaxf(fmaxf(zv[0], zv[1]), fmaxf(zv[2], zv[3]));
        #pragma unroll
        for (int off = 8; off; off >>= 1)
            mloc = fmaxf(mloc, __shfl_xor(mloc, off, 16));
        const float mnew  = fmaxf(m, mloc);
        const float alpha = __expf(m - mnew);

        float lloc = 0.0f;
        #pragma unroll
        for (int q4 = 0; q4 < 4; q4++) {
            const float p = __expf(zv[q4] - mnew);   // masked -> 0
            lloc += p;
            Ps[r][c + q4 * 16] = p;                  // intra-wave stage
        }
        #pragma unroll
        for (int off = 8; off; off >>= 1)
            lloc += __shfl_xor(lloc, off, 16);
        // NOTE: no barrier — Ps[r][*] written & read only by row r's wave;
        // per-wave DS program order + compiler lgkmcnt make it visible.

        // ---- PV: lane owns dims d=c, d=c+16 ----
        float pv0 = 0.0f, pv1 = 0.0f;
        #pragma unroll 4
        for (int j4 = 0; j4 < 64; j4 += 4) {
            const float4 pj = *(const float4*)&Ps[r][j4];
            const float2 va = Vs2[j4 + 0][c];
            const float2 vb = Vs2[j4 + 1][c];
            const float2 vc2 = Vs2[j4 + 2][c];
            const float2 vd = Vs2[j4 + 3][c];
            pv0 += pj.x * va.x + pj.y * vb.x + pj.z * vc2.x + pj.w * vd.x;
            pv1 += pj.x * va.y + pj.y * vb.y + pj.z * vc2.y + pj.w * vd.y;
        }

        m  = mnew;
        l  = l  * alpha + lloc;
        o0 = o0 * alpha + pv0;
        o1 = o1 * alpha + pv1;
    }

    const float inv = 1.0f / l;
    attn[ig * DM + h * DU + c]      = o0 * inv;
    attn[ig * DM + h * DU + c + 16] = o1 * inv;
}

// ---------------------------------------------------------------------------
// Kernel C: output projection  out = attn @ Wo + bo  (same BK=32 structure)
// ---------------------------------------------------------------------------
__global__ __launch_bounds__(256) void out_proj_kernel(
    const float* __restrict__ a, const float* __restrict__ W,
    const float* __restrict__ bias, float* __restrict__ dst)
{
    const int n0 = blockIdx.x * 64;
    const int m0 = blockIdx.y * 64;
    const int t  = threadIdx.x;
    const int tx = t & 15;
    const int ty = t >> 4;

    __shared__ float xs[32][68];   // transposed [k][row]
    __shared__ float wsh[32][68];

    float acc[4][4] = {};

    const int lrow = t & 63;
    const int lkc  = (t >> 6) * 8;
    const int wrow = t >> 4;
    const int wcol = (t & 15) * 4;

    for (int k0 = 0; k0 < DM; k0 += 32) {
        const float* xp = &a[(m0 + lrow) * DM + k0 + lkc];
        float4 xa = *(const float4*)xp;
        float4 xb = *(const float4*)(xp + 4);
        const float* wp = &W[(k0 + wrow) * DM + n0 + wcol];
        float4 wa = *(const float4*)wp;
        float4 wb = *(const float4*)(wp + 16 * DM);
        __syncthreads();
        xs[lkc + 0][lrow] = xa.x; xs[lkc + 1][lrow] = xa.y;
        xs[lkc + 2][lrow] = xa.z; xs[lkc + 3][lrow] = xa.w;
        xs[lkc + 4][lrow] = xb.x; xs[lkc + 5][lrow] = xb.y;
        xs[lkc + 6][lrow] = xb.z; xs[lkc + 7][lrow] = xb.w;
        *(float4*)&wsh[wrow][wcol]      = wa;
        *(float4*)&wsh[wrow + 16][wcol] = wb;
        __syncthreads();
        #pragma unroll
        for (int kk = 0; kk < 32; kk++) {
            float4 a4 = *(const float4*)&xs[kk][ty * 4];
            float4 b4 = *(const float4*)&wsh[kk][tx * 4];
            acc[0][0] += a4.x * b4.x; acc[0][1] += a4.x * b4.y;
            acc[0][2] += a4.x * b4.z; acc[0][3] += a4.x * b4.w;
            acc[1][0] += a4.y * b4.x; acc[1][1] += a4.y * b4.y;
            acc[1][2] += a4.y * b4.z; acc[1][3] += a4.y * b4.w;
            acc[2][0] += a4.z * b4.x; acc[2][1] += a4.z * b4.y;
            acc[2][2] += a4.z * b4.z; acc[2][3] += a4.z * b4.w;
            acc[3][0] += a4.w * b4.x; acc[3][1] += a4.w * b4.y;
            acc[3][2] += a4.w * b4.z; acc[3][3] += a4.w * b4.w;
        }
    }

    #pragma unroll
    for (int j = 0; j < 4; j++) {
        const int cidx = n0 + tx * 4 + j;
        const float bb = bias[cidx];
        #pragma unroll
        for (int i = 0; i < 4; i++) {
            const int row = m0 + ty * 4 + i;
            dst[row * DM + cidx] = acc[i][j] + bb;
        }
    }
}

// ---------------------------------------------------------------------------
extern "C" void kernel_launch(void* const* d_in, const int* in_sizes, int n_in,
                              void* d_out, int out_size, void* d_ws, size_t ws_size,
                              hipStream_t stream)
{
    const float* x  = (const float*)d_in[0];
    const float* Wq = (const float*)d_in[1];
    const float* bq = (const float*)d_in[2];
    const float* Wk = (const float*)d_in[3];
    const float* bk = (const float*)d_in[4];
    const float* Wv = (const float*)d_in[5];
    const float* bv = (const float*)d_in[6];
    const float* Wo = (const float*)d_in[7];
    const float* bo = (const float*)d_in[8];
    float* out = (float*)d_out;

    float* ws   = (float*)d_ws;
    float* q    = ws;                    // [8][1024][32]
    float* k    = q + 262144;
    float* v    = k + 262144;
    float* attn = v + 262144;            // [1024][256]

    qkv_proj_kernel<<<dim3(4, 16, 3), 256, 0, stream>>>(x, Wq, bq, Wk, bk, Wv, bv, q, k, v);
    attn_kernel<<<dim3(512), 256, 0, stream>>>(q, k, v, attn);
    out_proj_kernel<<<dim3(4, 16, 1), 256, 0, stream>>>(attn, Wo, bo, out);
}

// Round 4
// 119.715 us; speedup vs baseline: 1.4842x; 1.2033x over previous
//
#include <hip/hip_runtime.h>
#include <math.h>

#define S_LEN 1024
#define DM    256
#define DU    32
#define TEMPF 5.0f
#define NS    4          // attention j-splits (flash-decoding style)

// ---------------------------------------------------------------------------
// Kernel A: fused QKV projection.  out = act(x @ W + b), act = sigmoid for
// Q,K (mat 0,1), identity for V (mat 2). Writes [h][s][du] layout to ws.
// 32x64 tile, BK=32, double-buffered LDS (1 barrier/K-step), 384 blocks.
// ---------------------------------------------------------------------------
__global__ __launch_bounds__(256) void qkv_proj_kernel(
    const float* __restrict__ x,
    const float* __restrict__ Wq, const float* __restrict__ bq,
    const float* __restrict__ Wk, const float* __restrict__ bk,
    const float* __restrict__ Wv, const float* __restrict__ bv,
    float* __restrict__ qo, float* __restrict__ ko, float* __restrict__ vo)
{
    const int mat = blockIdx.z;
    const float* __restrict__ W    = (mat == 0) ? Wq : ((mat == 1) ? Wk : Wv);
    const float* __restrict__ bias = (mat == 0) ? bq : ((mat == 1) ? bk : bv);
    float* __restrict__ dst        = (mat == 0) ? qo : ((mat == 1) ? ko : vo);

    const int n0 = blockIdx.x * 64;
    const int m0 = blockIdx.y * 32;
    const int t  = threadIdx.x;
    const int tx = t & 15;        // cols tx*4..tx*4+3
    const int ty = t >> 4;        // rows ty*2, ty*2+1

    __shared__ float xs[2][32][36];   // transposed [k][row]
    __shared__ float wsh[2][32][68];  // [k][n]

    float acc[2][4] = {};

    const int xrow = t & 31;          // 0..31
    const int xkc  = (t >> 5) * 4;    // 0..28
    const int wrow = t >> 4;          // 0..15 (+16)
    const int wcol = (t & 15) * 4;

    // stage tile 0
    float4 xa = *(const float4*)&x[(m0 + xrow) * DM + xkc];
    float4 wa = *(const float4*)&W[wrow * DM + n0 + wcol];
    float4 wb = *(const float4*)&W[(wrow + 16) * DM + n0 + wcol];
    xs[0][xkc + 0][xrow] = xa.x; xs[0][xkc + 1][xrow] = xa.y;
    xs[0][xkc + 2][xrow] = xa.z; xs[0][xkc + 3][xrow] = xa.w;
    *(float4*)&wsh[0][wrow][wcol]      = wa;
    *(float4*)&wsh[0][wrow + 16][wcol] = wb;
    __syncthreads();

    int cur = 0;
    for (int k0 = 32; k0 < DM; k0 += 32) {
        // prefetch next tile (independent of compute; compiler hoists)
        xa = *(const float4*)&x[(m0 + xrow) * DM + k0 + xkc];
        wa = *(const float4*)&W[(k0 + wrow) * DM + n0 + wcol];
        wb = *(const float4*)&W[(k0 + wrow + 16) * DM + n0 + wcol];
        #pragma unroll
        for (int kk = 0; kk < 32; kk++) {
            float2 a2 = *(const float2*)&xs[cur][kk][ty * 2];
            float4 b4 = *(const float4*)&wsh[cur][kk][tx * 4];
            acc[0][0] += a2.x * b4.x; acc[0][1] += a2.x * b4.y;
            acc[0][2] += a2.x * b4.z; acc[0][3] += a2.x * b4.w;
            acc[1][0] += a2.y * b4.x; acc[1][1] += a2.y * b4.y;
            acc[1][2] += a2.y * b4.z; acc[1][3] += a2.y * b4.w;
        }
        const int nxt = cur ^ 1;
        xs[nxt][xkc + 0][xrow] = xa.x; xs[nxt][xkc + 1][xrow] = xa.y;
        xs[nxt][xkc + 2][xrow] = xa.z; xs[nxt][xkc + 3][xrow] = xa.w;
        *(float4*)&wsh[nxt][wrow][wcol]      = wa;
        *(float4*)&wsh[nxt][wrow + 16][wcol] = wb;
        __syncthreads();
        cur = nxt;
    }
    #pragma unroll
    for (int kk = 0; kk < 32; kk++) {
        float2 a2 = *(const float2*)&xs[cur][kk][ty * 2];
        float4 b4 = *(const float4*)&wsh[cur][kk][tx * 4];
        acc[0][0] += a2.x * b4.x; acc[0][1] += a2.x * b4.y;
        acc[0][2] += a2.x * b4.z; acc[0][3] += a2.x * b4.w;
        acc[1][0] += a2.y * b4.x; acc[1][1] += a2.y * b4.y;
        acc[1][2] += a2.y * b4.z; acc[1][3] += a2.y * b4.w;
    }

    #pragma unroll
    for (int j = 0; j < 4; j++) {
        const int cidx = n0 + tx * 4 + j;
        const float bb = bias[cidx];
        const int hh = cidx >> 5;
        const int dd = cidx & 31;
        #pragma unroll
        for (int i = 0; i < 2; i++) {
            const int row = m0 + ty * 2 + i;
            float val = acc[i][j] + bb;
            if (mat < 2) val = 1.0f / (1.0f + __expf(-val));   // sigmoid
            dst[hh * (S_LEN * DU) + row * DU + dd] = val;
        }
    }
}

// ---------------------------------------------------------------------------
// Kernel B: fuzzy-implication attention, flash-style, causal, j-SPLIT.
// Grid: 8 heads x 32 i-tiles (32 rows) x NS splits = 1024 blocks, heavy-first.
// Thread (r,c) handles rows {r, r+16} (Ks/Vs reads amortized over 2 rows)
// and output dims {c, c+16}. Split s does j-tiles jt = s, s+NS, ... < njt.
// Writes UNNORMALIZED partial o + (m,l) per row to ws; combine_kernel merges.
// ---------------------------------------------------------------------------
__global__ __launch_bounds__(256) void attn_kernel(
    const float* __restrict__ q, const float* __restrict__ k,
    const float* __restrict__ v,
    float* __restrict__ part_o, float* __restrict__ part_ml)
{
    const int bid = blockIdx.x;
    const int it2 = 31 - (bid >> 5);      // LPT: heavy i-tiles first
    const int sub = bid & 31;
    const int h   = sub & 7;
    const int s   = sub >> 3;             // split id 0..NS-1
    const int t   = threadIdx.x;
    const int r   = t >> 4;               // 0..15
    const int c   = t & 15;               // 0..15
    const int ig0 = it2 * 32 + r;
    const int ig1 = ig0 + 16;

    __shared__ float  Ks[64][36];
    __shared__ float2 Vs2[64][17];        // [j][c] = {V[j][c], V[j][c+16]}
    __shared__ float  Ps[32][68];         // rows 0..15 -> r, 16..31 -> r+16

    float qreg0[32], qreg1[32];
    {
        const float* q0 = q + h * (S_LEN * DU) + ig0 * DU;
        const float* q1 = q + h * (S_LEN * DU) + ig1 * DU;
        #pragma unroll
        for (int d4 = 0; d4 < 8; d4++) {
            float4 a = *(const float4*)&q0[d4 * 4];
            float4 b = *(const float4*)&q1[d4 * 4];
            qreg0[d4 * 4 + 0] = a.x; qreg0[d4 * 4 + 1] = a.y;
            qreg0[d4 * 4 + 2] = a.z; qreg0[d4 * 4 + 3] = a.w;
            qreg1[d4 * 4 + 0] = b.x; qreg1[d4 * 4 + 1] = b.y;
            qreg1[d4 * 4 + 2] = b.z; qreg1[d4 * 4 + 3] = b.w;
        }
    }

    float m0r = -1e30f, m1r = -1e30f, l0 = 0.0f, l1 = 0.0f;
    float o00 = 0.0f, o01 = 0.0f, o10 = 0.0f, o11 = 0.0f;

    const int njt = it2 / 2 + 1;          // j-tiles covering j <= it2*32+31
    for (int jt = s; jt < njt; jt += NS) {
        __syncthreads();
        {
            const int jr  = t >> 2;           // 0..63
            const int d0k = (t & 3) * 8;      // K: 8 contiguous
            const int dv  = (t & 3) * 4;      // V: 4 pairs
            const float* kp = k + h * (S_LEN * DU) + (jt * 64 + jr) * DU;
            const float* vp = v + h * (S_LEN * DU) + (jt * 64 + jr) * DU;
            float4 ka = *(const float4*)&kp[d0k];
            float4 kb = *(const float4*)&kp[d0k + 4];
            float4 va4 = *(const float4*)&vp[dv];
            float4 vb4 = *(const float4*)&vp[dv + 16];
            *(float4*)&Ks[jr][d0k]     = ka;
            *(float4*)&Ks[jr][d0k + 4] = kb;
            Vs2[jr][dv + 0] = make_float2(va4.x, vb4.x);
            Vs2[jr][dv + 1] = make_float2(va4.y, vb4.y);
            Vs2[jr][dv + 2] = make_float2(va4.z, vb4.z);
            Vs2[jr][dv + 3] = make_float2(va4.w, vb4.w);
        }
        __syncthreads();

        // ---- scores for cols jj = c+16*q4, both rows share Ks reads ----
        float zv0[4], zv1[4];
        #pragma unroll
        for (int q4 = 0; q4 < 4; q4++) {
            const int jj  = c + q4 * 16;
            const int jgl = jt * 64 + jj;
            float s0 = 0.0f, s1 = 0.0f;
            #pragma unroll
            for (int d = 0; d < 32; d += 4) {
                float4 k4 = *(const float4*)&Ks[jj][d];
                s0 += fmaxf(qreg0[d + 0] - k4.x, 0.0f)
                    + fmaxf(qreg0[d + 1] - k4.y, 0.0f)
                    + fmaxf(qreg0[d + 2] - k4.z, 0.0f)
                    + fmaxf(qreg0[d + 3] - k4.w, 0.0f);
                s1 += fmaxf(qreg1[d + 0] - k4.x, 0.0f)
                    + fmaxf(qreg1[d + 1] - k4.y, 0.0f)
                    + fmaxf(qreg1[d + 2] - k4.z, 0.0f)
                    + fmaxf(qreg1[d + 3] - k4.w, 0.0f);
            }
            zv0[q4] = (jgl <= ig0) ? (TEMPF - (TEMPF / 32.0f) * s0) : -1e30f;
            zv1[q4] = (jgl <= ig1) ? (TEMPF - (TEMPF / 32.0f) * s1) : -1e30f;
        }

        // ---- online softmax state (row = 16 consecutive lanes) ----
        float mloc0 = fmaxf(fmaxf(zv0[0], zv0[1]), fmaxf(zv0[2], zv0[3]));
        float mloc1 = fmaxf(fmaxf(zv1[0], zv1[1]), fmaxf(zv1[2], zv1[3]));
        #pragma unroll
        for (int off = 8; off; off >>= 1) {
            mloc0 = fmaxf(mloc0, __shfl_xor(mloc0, off, 16));
            mloc1 = fmaxf(mloc1, __shfl_xor(mloc1, off, 16));
        }
        const float mn0 = fmaxf(m0r, mloc0), mn1 = fmaxf(m1r, mloc1);
        const float al0 = __expf(m0r - mn0), al1 = __expf(m1r - mn1);

        float ll0 = 0.0f, ll1 = 0.0f;
        #pragma unroll
        for (int q4 = 0; q4 < 4; q4++) {
            const float p0 = __expf(zv0[q4] - mn0);
            const float p1 = __expf(zv1[q4] - mn1);
            ll0 += p0; ll1 += p1;
            Ps[r][c + q4 * 16]      = p0;    // intra-wave only -> no barrier
            Ps[r + 16][c + q4 * 16] = p1;
        }
        #pragma unroll
        for (int off = 8; off; off >>= 1) {
            ll0 += __shfl_xor(ll0, off, 16);
            ll1 += __shfl_xor(ll1, off, 16);
        }

        // ---- PV: Vs2 read once per j, serves both rows ----
        float pv00 = 0.0f, pv01 = 0.0f, pv10 = 0.0f, pv11 = 0.0f;
        #pragma unroll 4
        for (int j4 = 0; j4 < 64; j4 += 4) {
            float4 pj0 = *(const float4*)&Ps[r][j4];
            float4 pj1 = *(const float4*)&Ps[r + 16][j4];
            float2 va = Vs2[j4 + 0][c];
            float2 vb = Vs2[j4 + 1][c];
            float2 vc2 = Vs2[j4 + 2][c];
            float2 vd = Vs2[j4 + 3][c];
            pv00 += pj0.x * va.x + pj0.y * vb.x + pj0.z * vc2.x + pj0.w * vd.x;
            pv01 += pj0.x * va.y + pj0.y * vb.y + pj0.z * vc2.y + pj0.w * vd.y;
            pv10 += pj1.x * va.x + pj1.y * vb.x + pj1.z * vc2.x + pj1.w * vd.x;
            pv11 += pj1.x * va.y + pj1.y * vb.y + pj1.z * vc2.y + pj1.w * vd.y;
        }

        m0r = mn0; l0 = l0 * al0 + ll0; o00 = o00 * al0 + pv00; o01 = o01 * al0 + pv01;
        m1r = mn1; l1 = l1 * al1 + ll1; o10 = o10 * al1 + pv10; o11 = o11 * al1 + pv11;
    }

    // ---- write unnormalized partials ----
    const int pbase = (h * 32 + it2) * NS + s;
    float* po = part_o + pbase * 1024;
    po[r * 32 + c]             = o00;
    po[r * 32 + c + 16]        = o01;
    po[(r + 16) * 32 + c]      = o10;
    po[(r + 16) * 32 + c + 16] = o11;
    if (c == 0) {
        *(float2*)&part_ml[pbase * 64 + r * 2]        = make_float2(m0r, l0);
        *(float2*)&part_ml[pbase * 64 + (r + 16) * 2] = make_float2(m1r, l1);
    }
}

// ---------------------------------------------------------------------------
// Kernel B2: combine NS split partials -> attn [s][256]
// Grid 256 blocks (8 heads x 32 i-tiles), 256 threads.
// ---------------------------------------------------------------------------
__global__ __launch_bounds__(256) void combine_kernel(
    const float* __restrict__ part_o, const float* __restrict__ part_ml,
    float* __restrict__ attn)
{
    const int h   = blockIdx.x & 7;
    const int it2 = blockIdx.x >> 3;
    const int t   = threadIdx.x;
    const int r   = t >> 4;
    const int c   = t & 15;
    const int base = (h * 32 + it2) * NS;

    float2 ml0[NS], ml1[NS];
    #pragma unroll
    for (int s2 = 0; s2 < NS; s2++) {
        ml0[s2] = *(const float2*)&part_ml[(base + s2) * 64 + r * 2];
        ml1[s2] = *(const float2*)&part_ml[(base + s2) * 64 + (r + 16) * 2];
    }
    float M0 = ml0[0].x, M1 = ml1[0].x;
    #pragma unroll
    for (int s2 = 1; s2 < NS; s2++) {
        M0 = fmaxf(M0, ml0[s2].x);
        M1 = fmaxf(M1, ml1[s2].x);
    }
    float L0 = 0.0f, L1 = 0.0f, a00 = 0.0f, a01 = 0.0f, a10 = 0.0f, a11 = 0.0f;
    #pragma unroll
    for (int s2 = 0; s2 < NS; s2++) {
        const float w0 = __expf(ml0[s2].x - M0);
        const float w1 = __expf(ml1[s2].x - M1);
        L0 += w0 * ml0[s2].y;
        L1 += w1 * ml1[s2].y;
        const float* po = part_o + (base + s2) * 1024;
        a00 += w0 * po[r * 32 + c];
        a01 += w0 * po[r * 32 + c + 16];
        a10 += w1 * po[(r + 16) * 32 + c];
        a11 += w1 * po[(r + 16) * 32 + c + 16];
    }
    const float i0 = 1.0f / L0, i1 = 1.0f / L1;
    attn[(it2 * 32 + r) * DM + h * DU + c]           = a00 * i0;
    attn[(it2 * 32 + r) * DM + h * DU + c + 16]      = a01 * i0;
    attn[(it2 * 32 + r + 16) * DM + h * DU + c]      = a10 * i1;
    attn[(it2 * 32 + r + 16) * DM + h * DU + c + 16] = a11 * i1;
}

// ---------------------------------------------------------------------------
// Kernel C: output projection  out = attn @ Wo + bo.  32x32 tiles, dbuf,
// 256 blocks (vs 64 before — was leaving 75% of CUs idle).
// ---------------------------------------------------------------------------
__global__ __launch_bounds__(256) void out_proj_kernel(
    const float* __restrict__ a, const float* __restrict__ W,
    const float* __restrict__ bias, float* __restrict__ dst)
{
    const int n0 = blockIdx.x * 32;
    const int m0 = blockIdx.y * 32;
    const int t  = threadIdx.x;
    const int tx = t & 15;        // cols tx*2, tx*2+1
    const int ty = t >> 4;        // rows ty*2, ty*2+1

    __shared__ float xs[2][32][36];   // transposed [k][row]
    __shared__ float wsh[2][32][36];  // [k][n]

    float acc[2][2] = {};

    const int arow = t & 31;
    const int akc  = (t >> 5) * 4;
    const int wr   = t >> 3;          // 0..31
    const int wc   = (t & 7) * 4;     // 0..28

    float4 xa = *(const float4*)&a[(m0 + arow) * DM + akc];
    float4 wa = *(const float4*)&W[wr * DM + n0 + wc];
    xs[0][akc + 0][arow] = xa.x; xs[0][akc + 1][arow] = xa.y;
    xs[0][akc + 2][arow] = xa.z; xs[0][akc + 3][arow] = xa.w;
    *(float4*)&wsh[0][wr][wc] = wa;
    __syncthreads();

    int cur = 0;
    for (int k0 = 32; k0 < DM; k0 += 32) {
        xa = *(const float4*)&a[(m0 + arow) * DM + k0 + akc];
        wa = *(const float4*)&W[(k0 + wr) * DM + n0 + wc];
        #pragma unroll
        for (int kk = 0; kk < 32; kk++) {
            float2 a2 = *(const float2*)&xs[cur][kk][ty * 2];
            float2 b2 = *(const float2*)&wsh[cur][kk][tx * 2];
            acc[0][0] += a2.x * b2.x; acc[0][1] += a2.x * b2.y;
            acc[1][0] += a2.y * b2.x; acc[1][1] += a2.y * b2.y;
        }
        const int nxt = cur ^ 1;
        xs[nxt][akc + 0][arow] = xa.x; xs[nxt][akc + 1][arow] = xa.y;
        xs[nxt][akc + 2][arow] = xa.z; xs[nxt][akc + 3][arow] = xa.w;
        *(float4*)&wsh[nxt][wr][wc] = wa;
        __syncthreads();
        cur = nxt;
    }
    #pragma unroll
    for (int kk = 0; kk < 32; kk++) {
        float2 a2 = *(const float2*)&xs[cur][kk][ty * 2];
        float2 b2 = *(const float2*)&wsh[cur][kk][tx * 2];
        acc[0][0] += a2.x * b2.x; acc[0][1] += a2.x * b2.y;
        acc[1][0] += a2.y * b2.x; acc[1][1] += a2.y * b2.y;
    }

    #pragma unroll
    for (int j = 0; j < 2; j++) {
        const int cidx = n0 + tx * 2 + j;
        const float bb = bias[cidx];
        #pragma unroll
        for (int i = 0; i < 2; i++) {
            const int row = m0 + ty * 2 + i;
            dst[row * DM + cidx] = acc[i][j] + bb;
        }
    }
}

// ---------------------------------------------------------------------------
extern "C" void kernel_launch(void* const* d_in, const int* in_sizes, int n_in,
                              void* d_out, int out_size, void* d_ws, size_t ws_size,
                              hipStream_t stream)
{
    const float* x  = (const float*)d_in[0];
    const float* Wq = (const float*)d_in[1];
    const float* bq = (const float*)d_in[2];
    const float* Wk = (const float*)d_in[3];
    const float* bk = (const float*)d_in[4];
    const float* Wv = (const float*)d_in[5];
    const float* bv = (const float*)d_in[6];
    const float* Wo = (const float*)d_in[7];
    const float* bo = (const float*)d_in[8];
    float* out = (float*)d_out;

    float* ws      = (float*)d_ws;
    float* q       = ws;                      // [8][1024][32] = 262144
    float* k       = q + 262144;
    float* v       = k + 262144;
    float* attn    = v + 262144;              // [1024][256]  = 262144
    float* part_o  = attn + 262144;           // 8*32*NS*1024 = 1048576
    float* part_ml = part_o + 1048576;        // 8*32*NS*64   = 65536
    // total ~8.65 MB of workspace

    qkv_proj_kernel<<<dim3(4, 32, 3), 256, 0, stream>>>(x, Wq, bq, Wk, bk, Wv, bv, q, k, v);
    attn_kernel<<<dim3(8 * 32 * NS), 256, 0, stream>>>(q, k, v, part_o, part_ml);
    combine_kernel<<<dim3(256), 256, 0, stream>>>(part_o, part_ml, attn);
    out_proj_kernel<<<dim3(8, 32), 256, 0, stream>>>(attn, Wo, bo, out);
}